// Round 9
// baseline (179.452 us; speedup 1.0000x reference)
//
#include <hip/hip_runtime.h>
#include <math.h>

static constexpr int BB = 16;
static constexpr int NN = 100000;
static constexpr int GN = 4096;
static constexpr int GS = 64;
static constexpr int NP = BB * GN;       // 65536 problems
static constexpr int NE = GN * GS;       // 262144 entries
static constexpr int NBLK = (NN + 255) / 256;  // 391

__device__ __forceinline__ float wsum64(float v) {
#pragma unroll
  for (int off = 32; off > 0; off >>= 1) v += __shfl_xor(v, off, 64);
  return v;
}

// ---------- k_xpad: pad x (B,N,3)->(B,N,4), tpl (N,3)->(N,4); zero cnt/gtotal ----
__global__ __launch_bounds__(256) void k_xpad(
    const float4* __restrict__ x, const float4* __restrict__ tpl,
    float4* __restrict__ x4, float4* __restrict__ tpl4,
    int4* __restrict__ cnt4, int* __restrict__ gtotal) {
  int t = blockIdx.x * 256 + threadIdx.x;
  if (t == 0) *gtotal = 0;
  if (t < NN / 4) {
    cnt4[t] = make_int4(0, 0, 0, 0);
    float4 a = tpl[t * 3 + 0], b = tpl[t * 3 + 1], c = tpl[t * 3 + 2];
    tpl4[t * 4 + 0] = make_float4(a.x, a.y, a.z, 0.f);
    tpl4[t * 4 + 1] = make_float4(a.w, b.x, b.y, 0.f);
    tpl4[t * 4 + 2] = make_float4(b.z, b.w, c.x, 0.f);
    tpl4[t * 4 + 3] = make_float4(c.y, c.z, c.w, 0.f);
  }
  if (t >= BB * NN / 4) return;
  float4 a = x[t * 3 + 0], b = x[t * 3 + 1], c = x[t * 3 + 2];
  x4[t * 4 + 0] = make_float4(a.x, a.y, a.z, 0.f);
  x4[t * 4 + 1] = make_float4(a.w, b.x, b.y, 0.f);
  x4[t * 4 + 2] = make_float4(b.z, b.w, c.x, 0.f);
  x4[t * 4 + 3] = make_float4(c.y, c.z, c.w, 0.f);
}

// ---------- k_tpl: template pack + muY + counts histogram ----------
__global__ __launch_bounds__(256) void k_tpl(
    const float4* __restrict__ tpl4, const int* __restrict__ groups,
    float* __restrict__ Yg, float* __restrict__ GmY, int* __restrict__ cnt) {
  int g    = blockIdx.x * 4 + (threadIdx.x >> 6);
  int lane = threadIdx.x & 63;
  int idx = groups[g * GS + lane];
  atomicAdd(&cnt[idx], 1);
  float4 y = tpl4[idx];
  float* o = Yg + ((size_t)g * GS + lane) * 3;
  o[0] = y.x; o[1] = y.y; o[2] = y.z;
  float sy0 = wsum64(y.x), sy1 = wsum64(y.y), sy2 = wsum64(y.z);
  if (lane == 0) {
    const float inv = 1.0f / 64.0f;
    *(float4*)(GmY + (size_t)g * 4) =
        make_float4(sy0 * inv, sy1 * inv, sy2 * inv, 0.0f);
  }
}

// ---------- k_stats: 16-lane subgroups, 4 problems/wave, 4 points/lane ----------
__global__ __launch_bounds__(256) void k_stats(
    const float4* __restrict__ x4, const float* __restrict__ Yg,
    const float* __restrict__ GmY, const int* __restrict__ groups,
    float* __restrict__ Ht) {
  int bid  = (blockIdx.x & 7) * 512 + (blockIdx.x >> 3);  // XCD swizzle
  int wid4 = bid * 4 + (threadIdx.x >> 6);
  int lane = threadIdx.x & 63;
  int s    = lane >> 4;
  int l4   = lane & 15;
  int p = wid4 * 4 + s;
  int b = p >> 12;
  int g = p & (GN - 1);

  int4 iv = *(const int4*)(groups + (size_t)g * GS + l4 * 4);
  const float4* yv = (const float4*)(Yg + ((size_t)g * GS + l4 * 4) * 3);
  float4 ya = yv[0], yb = yv[1], yc = yv[2];

  const float4* xb4 = x4 + (size_t)b * NN;
  float sx0 = 0.f, sx1 = 0.f, sx2 = 0.f;
  float h00 = 0.f, h01 = 0.f, h02 = 0.f;
  float h10 = 0.f, h11 = 0.f, h12 = 0.f;
  float h20 = 0.f, h21 = 0.f, h22 = 0.f;

#define ACC(Y0, Y1, Y2, IDX)                                   \
  {                                                            \
    float4 xv = xb4[IDX];                                      \
    sx0 += xv.x; sx1 += xv.y; sx2 += xv.z;                     \
    h00 += (Y0) * xv.x; h01 += (Y0) * xv.y; h02 += (Y0) * xv.z;\
    h10 += (Y1) * xv.x; h11 += (Y1) * xv.y; h12 += (Y1) * xv.z;\
    h20 += (Y2) * xv.x; h21 += (Y2) * xv.y; h22 += (Y2) * xv.z;\
  }
  ACC(ya.x, ya.y, ya.z, iv.x);
  ACC(ya.w, yb.x, yb.y, iv.y);
  ACC(yb.z, yb.w, yc.x, iv.z);
  ACC(yc.y, yc.z, yc.w, iv.w);
#undef ACC

#define RED(V)                                                 \
  V += __shfl_xor(V, 8, 64); V += __shfl_xor(V, 4, 64);        \
  V += __shfl_xor(V, 2, 64); V += __shfl_xor(V, 1, 64);
  RED(sx0) RED(sx1) RED(sx2)
  RED(h00) RED(h01) RED(h02)
  RED(h10) RED(h11) RED(h12)
  RED(h20) RED(h21) RED(h22)
#undef RED

  if (l4 == 0) {
    const float inv = 1.0f / 64.0f;
    float4 m = *(const float4*)(GmY + (size_t)g * 4);
    float mx0 = sx0 * inv, mx1 = sx1 * inv, mx2 = sx2 * inv;
    float4 o0 = make_float4(mx0, mx1, mx2, h00 - m.x * sx0);
    float4 o1 = make_float4(h01 - m.x * sx1, h02 - m.x * sx2,
                            h10 - m.y * sx0, h11 - m.y * sx1);
    float4 o2 = make_float4(h12 - m.y * sx2, h20 - m.z * sx0,
                            h21 - m.z * sx1, h22 - m.z * sx2);
    float* o = Ht + (size_t)p * 12;
    *(float4*)(o + 0) = o0;
    *(float4*)(o + 4) = o1;
    *(float4*)(o + 8) = o2;
  }
}

// ------- k_svd: per-thread 3x3 SVD -> quaternion + t (32 B row) -------
#define JROT(P, Q, RR)                                                        \
  {                                                                           \
    float apq = K[P][Q];                                                      \
    if (fabsf(apq) > 1e-30f) {                                                \
      float app = K[P][P], aqq = K[Q][Q];                                     \
      float tau = (aqq - app) / (2.0f * apq);                                 \
      float tt = copysignf(1.0f, tau) / (fabsf(tau) + sqrtf(1.0f + tau*tau)); \
      float cc = 1.0f / sqrtf(1.0f + tt * tt);                                \
      float ss = tt * cc;                                                     \
      K[P][P] = app - tt * apq;                                               \
      K[Q][Q] = aqq + tt * apq;                                               \
      K[P][Q] = 0.0f; K[Q][P] = 0.0f;                                         \
      float krp = K[RR][P], krq = K[RR][Q];                                   \
      K[RR][P] = cc * krp - ss * krq; K[P][RR] = K[RR][P];                    \
      K[RR][Q] = ss * krp + cc * krq; K[Q][RR] = K[RR][Q];                    \
      float v0p = V[0][P], v0q = V[0][Q];                                     \
      float v1p = V[1][P], v1q = V[1][Q];                                     \
      float v2p = V[2][P], v2q = V[2][Q];                                     \
      V[0][P] = cc * v0p - ss * v0q; V[0][Q] = ss * v0p + cc * v0q;           \
      V[1][P] = cc * v1p - ss * v1q; V[1][Q] = ss * v1p + cc * v1q;           \
      V[2][P] = cc * v2p - ss * v2q; V[2][Q] = ss * v2p + cc * v2q;           \
    }                                                                         \
  }

#define FIN(AA, BBi, CC)                                                      \
  {                                                                           \
    float va0 = V[0][AA], va1 = V[1][AA], va2 = V[2][AA];                     \
    float vb0 = V[0][BBi], vb1 = V[1][BBi], vb2 = V[2][BBi];                  \
    float vc0 = V[0][CC], vc1 = V[1][CC], vc2 = V[2][CC];                     \
    float ua0 = A[0][0]*va0 + A[0][1]*va1 + A[0][2]*va2;                      \
    float ua1 = A[1][0]*va0 + A[1][1]*va1 + A[1][2]*va2;                      \
    float ua2 = A[2][0]*va0 + A[2][1]*va1 + A[2][2]*va2;                      \
    float il = 1.0f / sqrtf(ua0*ua0 + ua1*ua1 + ua2*ua2 + 1e-30f);            \
    ua0 *= il; ua1 *= il; ua2 *= il;                                          \
    float ub0 = A[0][0]*vb0 + A[0][1]*vb1 + A[0][2]*vb2;                      \
    float ub1 = A[1][0]*vb0 + A[1][1]*vb1 + A[1][2]*vb2;                      \
    float ub2 = A[2][0]*vb0 + A[2][1]*vb1 + A[2][2]*vb2;                      \
    il = 1.0f / sqrtf(ub0*ub0 + ub1*ub1 + ub2*ub2 + 1e-30f);                  \
    ub0 *= il; ub1 *= il; ub2 *= il;                                          \
    float dd = ua0*ub0 + ua1*ub1 + ua2*ub2;                                   \
    ub0 -= dd * ua0; ub1 -= dd * ua1; ub2 -= dd * ua2;                        \
    il = 1.0f / sqrtf(ub0*ub0 + ub1*ub1 + ub2*ub2 + 1e-30f);                  \
    ub0 *= il; ub1 *= il; ub2 *= il;                                          \
    float uc0 = ua1*ub2 - ua2*ub1;                                            \
    float uc1 = ua2*ub0 - ua0*ub2;                                            \
    float uc2 = ua0*ub1 - ua1*ub0;                                            \
    R[0][0] = va0*ua0 + vb0*ub0 + dsg*vc0*uc0;                                \
    R[0][1] = va0*ua1 + vb0*ub1 + dsg*vc0*uc1;                                \
    R[0][2] = va0*ua2 + vb0*ub2 + dsg*vc0*uc2;                                \
    R[1][0] = va1*ua0 + vb1*ub0 + dsg*vc1*uc0;                                \
    R[1][1] = va1*ua1 + vb1*ub1 + dsg*vc1*uc1;                                \
    R[1][2] = va1*ua2 + vb1*ub2 + dsg*vc1*uc2;                                \
    R[2][0] = va2*ua0 + vb2*ub0 + dsg*vc2*uc0;                                \
    R[2][1] = va2*ua1 + vb2*ub1 + dsg*vc2*uc1;                                \
    R[2][2] = va2*ua2 + vb2*ub2 + dsg*vc2*uc2;                                \
  }

__global__ __launch_bounds__(256) void k_svd(
    const float* __restrict__ Ht, const float* __restrict__ GmY,
    float* __restrict__ Qt) {
  int p = blockIdx.x * 256 + threadIdx.x;
  if (p >= NP) return;
  int g = p & (GN - 1);
  const float* h = Ht + (size_t)p * 12;
  float4 f0 = *(const float4*)(h + 0);
  float4 f1 = *(const float4*)(h + 4);
  float4 f2 = *(const float4*)(h + 8);
  float4 m  = *(const float4*)(GmY + (size_t)g * 4);
  float mx0 = f0.x, mx1 = f0.y, mx2 = f0.z;
  float my0 = m.x, my1 = m.y, my2 = m.z;
  float A[3][3];
  A[0][0] = f0.w; A[0][1] = f1.x; A[0][2] = f1.y;
  A[1][0] = f1.z; A[1][1] = f1.w; A[1][2] = f2.x;
  A[2][0] = f2.y; A[2][1] = f2.z; A[2][2] = f2.w;

  float K[3][3];
#pragma unroll
  for (int i = 0; i < 3; ++i)
#pragma unroll
    for (int j = 0; j < 3; ++j)
      K[i][j] = A[0][i]*A[0][j] + A[1][i]*A[1][j] + A[2][i]*A[2][j];

  float V[3][3] = {{1.f,0.f,0.f},{0.f,1.f,0.f},{0.f,0.f,1.f}};
#pragma unroll
  for (int sweep = 0; sweep < 5; ++sweep) {
    JROT(0, 1, 2);
    JROT(0, 2, 1);
    JROT(1, 2, 0);
  }

  float d0 = K[0][0], d1 = K[1][1], d2 = K[2][2];
  float detV = V[0][0]*(V[1][1]*V[2][2] - V[1][2]*V[2][1])
             - V[0][1]*(V[1][0]*V[2][2] - V[1][2]*V[2][0])
             + V[0][2]*(V[1][0]*V[2][1] - V[1][1]*V[2][0]);
  float dsg = (detV < 0.0f) ? -1.0f : 1.0f;

  float R[3][3];
  if (d0 <= d1 && d0 <= d2) {
    FIN(1, 2, 0);
  } else if (d1 <= d0 && d1 <= d2) {
    FIN(2, 0, 1);
  } else {
    FIN(0, 1, 2);
  }

  float t0 = mx0 - (R[0][0]*my0 + R[0][1]*my1 + R[0][2]*my2);
  float t1 = mx1 - (R[1][0]*my0 + R[1][1]*my1 + R[1][2]*my2);
  float t2 = mx2 - (R[2][0]*my0 + R[2][1]*my1 + R[2][2]*my2);

  // R (proper rotation, det=+1) -> quaternion (x,y,z,w)
  float qw, qx, qy, qz;
  float tr = R[0][0] + R[1][1] + R[2][2];
  if (tr > 0.f) {
    float S = sqrtf(tr + 1.0f) * 2.0f;
    qw = 0.25f * S;
    qx = (R[2][1] - R[1][2]) / S;
    qy = (R[0][2] - R[2][0]) / S;
    qz = (R[1][0] - R[0][1]) / S;
  } else if (R[0][0] > R[1][1] && R[0][0] > R[2][2]) {
    float S = sqrtf(1.0f + R[0][0] - R[1][1] - R[2][2]) * 2.0f;
    qw = (R[2][1] - R[1][2]) / S;
    qx = 0.25f * S;
    qy = (R[0][1] + R[1][0]) / S;
    qz = (R[0][2] + R[2][0]) / S;
  } else if (R[1][1] > R[2][2]) {
    float S = sqrtf(1.0f + R[1][1] - R[0][0] - R[2][2]) * 2.0f;
    qw = (R[0][2] - R[2][0]) / S;
    qx = (R[0][1] + R[1][0]) / S;
    qy = 0.25f * S;
    qz = (R[1][2] + R[2][1]) / S;
  } else {
    float S = sqrtf(1.0f + R[2][2] - R[0][0] - R[1][1]) * 2.0f;
    qw = (R[1][0] - R[0][1]) / S;
    qx = (R[0][2] + R[2][0]) / S;
    qy = (R[1][2] + R[2][1]) / S;
    qz = 0.25f * S;
  }
  float il2 = 1.0f / sqrtf(qw*qw + qx*qx + qy*qy + qz*qz);
  qw *= il2; qx *= il2; qy *= il2; qz *= il2;

  float* o = Qt + (size_t)p * 8;  // 32 B row
  *(float4*)(o + 0) = make_float4(qx, qy, qz, qw);
  *(float4*)(o + 4) = make_float4(t0, t1, t2, 0.f);
}

// ---------- k_alloc: CSR row allocation via wave prefix + 1 atomic/wave ----------
__global__ __launch_bounds__(256) void k_alloc(
    const int* __restrict__ cnt, int* __restrict__ gtotal,
    int2* __restrict__ rs_cnt, int* __restrict__ cursor) {
  int t = blockIdx.x * 256 + threadIdx.x;
  int lane = threadIdx.x & 63;
  int v = (t < NN) ? cnt[t] : 0;
  int sc = v;  // inclusive prefix within wave
#pragma unroll
  for (int off = 1; off < 64; off <<= 1) {
    int u = __shfl_up(sc, off, 64);
    if (lane >= off) sc += u;
  }
  int wtotal = __shfl(sc, 63, 64);
  int base = 0;
  if (lane == 63) base = atomicAdd(gtotal, wtotal);
  base = __shfl(base, 63, 64);
  if (t < NN) {
    rs_cnt[t] = make_int2(base + sc - v, v);
    cursor[t] = 0;
  }
}

// ---------- k_fill: per-entry slot assignment (coalesced eslot write) ----------
__global__ __launch_bounds__(256) void k_fill(
    const int* __restrict__ groups, const int2* __restrict__ rs_cnt,
    int* __restrict__ cursor, int* __restrict__ eslot) {
  int e = blockIdx.x * 256 + threadIdx.x;
  if (e >= NE) return;
  int n = groups[e];
  int pos = atomicAdd(&cursor[n], 1);
  eslot[e] = rs_cnt[n].x + pos;
}

// ---------- k_proj: entry-parallel projection, all 16 b inside ----------
// wave = 64 consecutive e -> same g -> Qt loads are wave-broadcast.
// No divergence, no dependent-load loop; stores scatter into CSR slots.
__global__ __launch_bounds__(256) void k_proj(
    const int* __restrict__ groups, const int* __restrict__ eslot,
    const float4* __restrict__ tpl4, const float* __restrict__ Qt,
    float* __restrict__ proj) {
  int e = blockIdx.x * 256 + threadIdx.x;
  int g = e >> 6;
  int n = groups[e];
  int slot = eslot[e];
  float4 y = tpl4[n];
#pragma unroll 4
  for (int b = 0; b < BB; ++b) {
    const float* qt = Qt + ((size_t)b * GN + g) * 8;
    float4 q  = *(const float4*)(qt + 0);   // qx qy qz qw
    float4 tv = *(const float4*)(qt + 4);   // t0 t1 t2 -
    float tx = 2.f * (q.y * y.z - q.z * y.y);
    float ty = 2.f * (q.z * y.x - q.x * y.z);
    float tz = 2.f * (q.x * y.y - q.y * y.x);
    float p0 = y.x + q.w * tx + (q.y * tz - q.z * ty) + tv.x;
    float p1 = y.y + q.w * ty + (q.z * tx - q.x * tz) + tv.y;
    float p2 = y.z + q.w * tz + (q.x * ty - q.y * tx) + tv.z;
    float* o = proj + ((size_t)b * NE + (size_t)slot) * 3;
    o[0] = p0; o[1] = p1; o[2] = p2;
  }
}

// ---------- k_reduce: thread per (b,n): contiguous CSR-row sum ----------
__global__ __launch_bounds__(256) void k_reduce(
    const int2* __restrict__ rs_cnt, const float* __restrict__ proj,
    float* __restrict__ out) {
  int n = blockIdx.x * 256 + threadIdx.x;
  if (n >= NN) return;
  int b = blockIdx.y;
  int2 rc = rs_cnt[n];
  const float* pp = proj + ((size_t)b * NE + (size_t)rc.x) * 3;
  float p0 = 0.f, p1 = 0.f, p2 = 0.f;
  for (int j = 0; j < rc.y; ++j) {
    p0 += pp[j * 3 + 0];
    p1 += pp[j * 3 + 1];
    p2 += pp[j * 3 + 2];
  }
  float inv = 1.0f / fmaxf((float)rc.y, 1.0f);
  float* o = out + ((size_t)b * NN + (size_t)n) * 3;
  *(float3*)o = make_float3(p0 * inv, p1 * inv, p2 * inv);
}

extern "C" void kernel_launch(void* const* d_in, const int* in_sizes, int n_in,
                              void* d_out, int out_size, void* d_ws, size_t ws_size,
                              hipStream_t stream) {
  const float* x      = (const float*)d_in[0];  // (B,N,3) f32
  const float* tpl    = (const float*)d_in[1];  // (N,3) f32
  const int*   groups = (const int*)d_in[2];    // (GN,GS) i32
  float* out = (float*)d_out;

  char* ws = (char*)d_ws;
  // Non-aliased layout, ~90.5 MB (ws is 256 MB):
  size_t o_x4   = 0;                        // 25,600,000
  size_t o_tpl4 = o_x4 + 25600000;          //  1,600,000
  size_t o_yg   = o_tpl4 + 1600000;         //  3,145,728
  size_t o_ht   = o_yg + 3145728;           //  3,145,728
  size_t o_qt   = o_ht + 3145728;           //  2,097,152 (32 B rows)
  size_t o_gmy  = o_qt + 2097152;           //     65,536
  size_t o_cnt  = o_gmy + 65536;            //    400,000
  size_t o_rsc  = o_cnt + 400000;           //    800,000
  size_t o_cur  = o_rsc + 800000;           //    400,000
  size_t o_gt   = o_cur + 400000;           //         64
  size_t o_esl  = o_gt + 64;                //  1,048,576
  size_t o_proj = o_esl + 1048576;          // 50,331,648 (16*NE*12 B)
  float* x4     = (float*)(ws + o_x4);
  float* tpl4   = (float*)(ws + o_tpl4);
  float* Yg     = (float*)(ws + o_yg);
  float* Ht     = (float*)(ws + o_ht);
  float* Qt     = (float*)(ws + o_qt);
  float* GmY    = (float*)(ws + o_gmy);
  int*   cnt    = (int*)(ws + o_cnt);
  int2*  rs_cnt = (int2*)(ws + o_rsc);
  int*   cursor = (int*)(ws + o_cur);
  int*   gtotal = (int*)(ws + o_gt);
  int*   eslot  = (int*)(ws + o_esl);
  float* proj   = (float*)(ws + o_proj);

  k_xpad<<<(BB * NN / 4 + 255) / 256, 256, 0, stream>>>(
      (const float4*)x, (const float4*)tpl, (float4*)x4, (float4*)tpl4,
      (int4*)cnt, gtotal);
  k_tpl<<<GN / 4, 256, 0, stream>>>((const float4*)tpl4, groups, Yg, GmY, cnt);
  k_stats<<<NP / 16, 256, 0, stream>>>((const float4*)x4, Yg, GmY, groups, Ht);
  k_alloc<<<NBLK, 256, 0, stream>>>(cnt, gtotal, rs_cnt, cursor);
  k_fill<<<NE / 256, 256, 0, stream>>>(groups, rs_cnt, cursor, eslot);
  k_svd<<<NP / 256, 256, 0, stream>>>(Ht, GmY, Qt);
  k_proj<<<NE / 256, 256, 0, stream>>>(groups, eslot, (const float4*)tpl4, Qt, proj);
  k_reduce<<<dim3(NBLK, BB), 256, 0, stream>>>(rs_cnt, proj, out);
}

// Round 10
// 141.516 us; speedup vs baseline: 1.2681x; 1.2681x over previous
//
#include <hip/hip_runtime.h>
#include <math.h>

static constexpr int BB = 16;
static constexpr int NN = 100000;
static constexpr int GN = 4096;
static constexpr int GS = 64;
static constexpr int NP = BB * GN;       // 65536 problems
static constexpr int NE = GN * GS;       // 262144 entries
static constexpr int NBLK = (NN + 255) / 256;  // 391

__device__ __forceinline__ float wsum64(float v) {
#pragma unroll
  for (int off = 32; off > 0; off >>= 1) v += __shfl_xor(v, off, 64);
  return v;
}

// ---------- k_xpad: pad x (B,N,3)->(B,N,4), tpl (N,3)->(N,4); zero cnt/gtotal ----
__global__ __launch_bounds__(256) void k_xpad(
    const float4* __restrict__ x, const float4* __restrict__ tpl,
    float4* __restrict__ x4, float4* __restrict__ tpl4,
    int4* __restrict__ cnt4, int* __restrict__ gtotal) {
  int t = blockIdx.x * 256 + threadIdx.x;
  if (t == 0) *gtotal = 0;
  if (t < NN / 4) {
    cnt4[t] = make_int4(0, 0, 0, 0);
    float4 a = tpl[t * 3 + 0], b = tpl[t * 3 + 1], c = tpl[t * 3 + 2];
    tpl4[t * 4 + 0] = make_float4(a.x, a.y, a.z, 0.f);
    tpl4[t * 4 + 1] = make_float4(a.w, b.x, b.y, 0.f);
    tpl4[t * 4 + 2] = make_float4(b.z, b.w, c.x, 0.f);
    tpl4[t * 4 + 3] = make_float4(c.y, c.z, c.w, 0.f);
  }
  if (t >= BB * NN / 4) return;
  float4 a = x[t * 3 + 0], b = x[t * 3 + 1], c = x[t * 3 + 2];
  x4[t * 4 + 0] = make_float4(a.x, a.y, a.z, 0.f);
  x4[t * 4 + 1] = make_float4(a.w, b.x, b.y, 0.f);
  x4[t * 4 + 2] = make_float4(b.z, b.w, c.x, 0.f);
  x4[t * 4 + 3] = make_float4(c.y, c.z, c.w, 0.f);
}

// ---------- k_tpl: template pack + muY + counts histogram ----------
__global__ __launch_bounds__(256) void k_tpl(
    const float4* __restrict__ tpl4, const int* __restrict__ groups,
    float* __restrict__ Yg, float* __restrict__ GmY, int* __restrict__ cnt) {
  int g    = blockIdx.x * 4 + (threadIdx.x >> 6);
  int lane = threadIdx.x & 63;
  int idx = groups[g * GS + lane];
  atomicAdd(&cnt[idx], 1);
  float4 y = tpl4[idx];
  float* o = Yg + ((size_t)g * GS + lane) * 3;
  o[0] = y.x; o[1] = y.y; o[2] = y.z;
  float sy0 = wsum64(y.x), sy1 = wsum64(y.y), sy2 = wsum64(y.z);
  if (lane == 0) {
    const float inv = 1.0f / 64.0f;
    *(float4*)(GmY + (size_t)g * 4) =
        make_float4(sy0 * inv, sy1 * inv, sy2 * inv, 0.0f);
  }
}

// ---------- k_stats: 16-lane subgroups, 4 problems/wave, 4 points/lane ----------
__global__ __launch_bounds__(256) void k_stats(
    const float4* __restrict__ x4, const float* __restrict__ Yg,
    const float* __restrict__ GmY, const int* __restrict__ groups,
    float* __restrict__ Ht) {
  int bid  = (blockIdx.x & 7) * 512 + (blockIdx.x >> 3);  // XCD swizzle
  int wid4 = bid * 4 + (threadIdx.x >> 6);
  int lane = threadIdx.x & 63;
  int s    = lane >> 4;
  int l4   = lane & 15;
  int p = wid4 * 4 + s;
  int b = p >> 12;
  int g = p & (GN - 1);

  int4 iv = *(const int4*)(groups + (size_t)g * GS + l4 * 4);
  const float4* yv = (const float4*)(Yg + ((size_t)g * GS + l4 * 4) * 3);
  float4 ya = yv[0], yb = yv[1], yc = yv[2];

  const float4* xb4 = x4 + (size_t)b * NN;
  float sx0 = 0.f, sx1 = 0.f, sx2 = 0.f;
  float h00 = 0.f, h01 = 0.f, h02 = 0.f;
  float h10 = 0.f, h11 = 0.f, h12 = 0.f;
  float h20 = 0.f, h21 = 0.f, h22 = 0.f;

#define ACC(Y0, Y1, Y2, IDX)                                   \
  {                                                            \
    float4 xv = xb4[IDX];                                      \
    sx0 += xv.x; sx1 += xv.y; sx2 += xv.z;                     \
    h00 += (Y0) * xv.x; h01 += (Y0) * xv.y; h02 += (Y0) * xv.z;\
    h10 += (Y1) * xv.x; h11 += (Y1) * xv.y; h12 += (Y1) * xv.z;\
    h20 += (Y2) * xv.x; h21 += (Y2) * xv.y; h22 += (Y2) * xv.z;\
  }
  ACC(ya.x, ya.y, ya.z, iv.x);
  ACC(ya.w, yb.x, yb.y, iv.y);
  ACC(yb.z, yb.w, yc.x, iv.z);
  ACC(yc.y, yc.z, yc.w, iv.w);
#undef ACC

#define RED(V)                                                 \
  V += __shfl_xor(V, 8, 64); V += __shfl_xor(V, 4, 64);        \
  V += __shfl_xor(V, 2, 64); V += __shfl_xor(V, 1, 64);
  RED(sx0) RED(sx1) RED(sx2)
  RED(h00) RED(h01) RED(h02)
  RED(h10) RED(h11) RED(h12)
  RED(h20) RED(h21) RED(h22)
#undef RED

  if (l4 == 0) {
    const float inv = 1.0f / 64.0f;
    float4 m = *(const float4*)(GmY + (size_t)g * 4);
    float mx0 = sx0 * inv, mx1 = sx1 * inv, mx2 = sx2 * inv;
    float4 o0 = make_float4(mx0, mx1, mx2, h00 - m.x * sx0);
    float4 o1 = make_float4(h01 - m.x * sx1, h02 - m.x * sx2,
                            h10 - m.y * sx0, h11 - m.y * sx1);
    float4 o2 = make_float4(h12 - m.y * sx2, h20 - m.z * sx0,
                            h21 - m.z * sx1, h22 - m.z * sx2);
    float* o = Ht + (size_t)p * 12;
    *(float4*)(o + 0) = o0;
    *(float4*)(o + 4) = o1;
    *(float4*)(o + 8) = o2;
  }
}

// ------- k_svd: per-thread 3x3 SVD -> quaternion + t (32 B row) -------
#define JROT(P, Q, RR)                                                        \
  {                                                                           \
    float apq = K[P][Q];                                                      \
    if (fabsf(apq) > 1e-30f) {                                                \
      float app = K[P][P], aqq = K[Q][Q];                                     \
      float tau = (aqq - app) / (2.0f * apq);                                 \
      float tt = copysignf(1.0f, tau) / (fabsf(tau) + sqrtf(1.0f + tau*tau)); \
      float cc = 1.0f / sqrtf(1.0f + tt * tt);                                \
      float ss = tt * cc;                                                     \
      K[P][P] = app - tt * apq;                                               \
      K[Q][Q] = aqq + tt * apq;                                               \
      K[P][Q] = 0.0f; K[Q][P] = 0.0f;                                         \
      float krp = K[RR][P], krq = K[RR][Q];                                   \
      K[RR][P] = cc * krp - ss * krq; K[P][RR] = K[RR][P];                    \
      K[RR][Q] = ss * krp + cc * krq; K[Q][RR] = K[RR][Q];                    \
      float v0p = V[0][P], v0q = V[0][Q];                                     \
      float v1p = V[1][P], v1q = V[1][Q];                                     \
      float v2p = V[2][P], v2q = V[2][Q];                                     \
      V[0][P] = cc * v0p - ss * v0q; V[0][Q] = ss * v0p + cc * v0q;           \
      V[1][P] = cc * v1p - ss * v1q; V[1][Q] = ss * v1p + cc * v1q;           \
      V[2][P] = cc * v2p - ss * v2q; V[2][Q] = ss * v2p + cc * v2q;           \
    }                                                                         \
  }

#define FIN(AA, BBi, CC)                                                      \
  {                                                                           \
    float va0 = V[0][AA], va1 = V[1][AA], va2 = V[2][AA];                     \
    float vb0 = V[0][BBi], vb1 = V[1][BBi], vb2 = V[2][BBi];                  \
    float vc0 = V[0][CC], vc1 = V[1][CC], vc2 = V[2][CC];                     \
    float ua0 = A[0][0]*va0 + A[0][1]*va1 + A[0][2]*va2;                      \
    float ua1 = A[1][0]*va0 + A[1][1]*va1 + A[1][2]*va2;                      \
    float ua2 = A[2][0]*va0 + A[2][1]*va1 + A[2][2]*va2;                      \
    float il = 1.0f / sqrtf(ua0*ua0 + ua1*ua1 + ua2*ua2 + 1e-30f);            \
    ua0 *= il; ua1 *= il; ua2 *= il;                                          \
    float ub0 = A[0][0]*vb0 + A[0][1]*vb1 + A[0][2]*vb2;                      \
    float ub1 = A[1][0]*vb0 + A[1][1]*vb1 + A[1][2]*vb2;                      \
    float ub2 = A[2][0]*vb0 + A[2][1]*vb1 + A[2][2]*vb2;                      \
    il = 1.0f / sqrtf(ub0*ub0 + ub1*ub1 + ub2*ub2 + 1e-30f);                  \
    ub0 *= il; ub1 *= il; ub2 *= il;                                          \
    float dd = ua0*ub0 + ua1*ub1 + ua2*ub2;                                   \
    ub0 -= dd * ua0; ub1 -= dd * ua1; ub2 -= dd * ua2;                        \
    il = 1.0f / sqrtf(ub0*ub0 + ub1*ub1 + ub2*ub2 + 1e-30f);                  \
    ub0 *= il; ub1 *= il; ub2 *= il;                                          \
    float uc0 = ua1*ub2 - ua2*ub1;                                            \
    float uc1 = ua2*ub0 - ua0*ub2;                                            \
    float uc2 = ua0*ub1 - ua1*ub0;                                            \
    R[0][0] = va0*ua0 + vb0*ub0 + dsg*vc0*uc0;                                \
    R[0][1] = va0*ua1 + vb0*ub1 + dsg*vc0*uc1;                                \
    R[0][2] = va0*ua2 + vb0*ub2 + dsg*vc0*uc2;                                \
    R[1][0] = va1*ua0 + vb1*ub0 + dsg*vc1*uc0;                                \
    R[1][1] = va1*ua1 + vb1*ub1 + dsg*vc1*uc1;                                \
    R[1][2] = va1*ua2 + vb1*ub2 + dsg*vc1*uc2;                                \
    R[2][0] = va2*ua0 + vb2*ub0 + dsg*vc2*uc0;                                \
    R[2][1] = va2*ua1 + vb2*ub1 + dsg*vc2*uc1;                                \
    R[2][2] = va2*ua2 + vb2*ub2 + dsg*vc2*uc2;                                \
  }

__global__ __launch_bounds__(256) void k_svd(
    const float* __restrict__ Ht, const float* __restrict__ GmY,
    float* __restrict__ Qt) {
  int p = blockIdx.x * 256 + threadIdx.x;
  if (p >= NP) return;
  int g = p & (GN - 1);
  const float* h = Ht + (size_t)p * 12;
  float4 f0 = *(const float4*)(h + 0);
  float4 f1 = *(const float4*)(h + 4);
  float4 f2 = *(const float4*)(h + 8);
  float4 m  = *(const float4*)(GmY + (size_t)g * 4);
  float mx0 = f0.x, mx1 = f0.y, mx2 = f0.z;
  float my0 = m.x, my1 = m.y, my2 = m.z;
  float A[3][3];
  A[0][0] = f0.w; A[0][1] = f1.x; A[0][2] = f1.y;
  A[1][0] = f1.z; A[1][1] = f1.w; A[1][2] = f2.x;
  A[2][0] = f2.y; A[2][1] = f2.z; A[2][2] = f2.w;

  float K[3][3];
#pragma unroll
  for (int i = 0; i < 3; ++i)
#pragma unroll
    for (int j = 0; j < 3; ++j)
      K[i][j] = A[0][i]*A[0][j] + A[1][i]*A[1][j] + A[2][i]*A[2][j];

  float V[3][3] = {{1.f,0.f,0.f},{0.f,1.f,0.f},{0.f,0.f,1.f}};
#pragma unroll
  for (int sweep = 0; sweep < 5; ++sweep) {
    JROT(0, 1, 2);
    JROT(0, 2, 1);
    JROT(1, 2, 0);
  }

  float d0 = K[0][0], d1 = K[1][1], d2 = K[2][2];
  float detV = V[0][0]*(V[1][1]*V[2][2] - V[1][2]*V[2][1])
             - V[0][1]*(V[1][0]*V[2][2] - V[1][2]*V[2][0])
             + V[0][2]*(V[1][0]*V[2][1] - V[1][1]*V[2][0]);
  float dsg = (detV < 0.0f) ? -1.0f : 1.0f;

  float R[3][3];
  if (d0 <= d1 && d0 <= d2) {
    FIN(1, 2, 0);
  } else if (d1 <= d0 && d1 <= d2) {
    FIN(2, 0, 1);
  } else {
    FIN(0, 1, 2);
  }

  float t0 = mx0 - (R[0][0]*my0 + R[0][1]*my1 + R[0][2]*my2);
  float t1 = mx1 - (R[1][0]*my0 + R[1][1]*my1 + R[1][2]*my2);
  float t2 = mx2 - (R[2][0]*my0 + R[2][1]*my1 + R[2][2]*my2);

  // R (proper rotation, det=+1) -> quaternion (x,y,z,w)
  float qw, qx, qy, qz;
  float tr = R[0][0] + R[1][1] + R[2][2];
  if (tr > 0.f) {
    float S = sqrtf(tr + 1.0f) * 2.0f;
    qw = 0.25f * S;
    qx = (R[2][1] - R[1][2]) / S;
    qy = (R[0][2] - R[2][0]) / S;
    qz = (R[1][0] - R[0][1]) / S;
  } else if (R[0][0] > R[1][1] && R[0][0] > R[2][2]) {
    float S = sqrtf(1.0f + R[0][0] - R[1][1] - R[2][2]) * 2.0f;
    qw = (R[2][1] - R[1][2]) / S;
    qx = 0.25f * S;
    qy = (R[0][1] + R[1][0]) / S;
    qz = (R[0][2] + R[2][0]) / S;
  } else if (R[1][1] > R[2][2]) {
    float S = sqrtf(1.0f + R[1][1] - R[0][0] - R[2][2]) * 2.0f;
    qw = (R[0][2] - R[2][0]) / S;
    qx = (R[0][1] + R[1][0]) / S;
    qy = 0.25f * S;
    qz = (R[1][2] + R[2][1]) / S;
  } else {
    float S = sqrtf(1.0f + R[2][2] - R[0][0] - R[1][1]) * 2.0f;
    qw = (R[1][0] - R[0][1]) / S;
    qx = (R[0][2] + R[2][0]) / S;
    qy = (R[1][2] + R[2][1]) / S;
    qz = 0.25f * S;
  }
  float il2 = 1.0f / sqrtf(qw*qw + qx*qx + qy*qy + qz*qz);
  qw *= il2; qx *= il2; qy *= il2; qz *= il2;

  float* o = Qt + (size_t)p * 8;  // 32 B row
  *(float4*)(o + 0) = make_float4(qx, qy, qz, qw);
  *(float4*)(o + 4) = make_float4(t0, t1, t2, 0.f);
}

// ---- k_alloc: 4-aligned CSR row allocation + zero-pad entries tail ----
__global__ __launch_bounds__(256) void k_alloc(
    const int* __restrict__ cnt, int* __restrict__ gtotal,
    int2* __restrict__ rs_cnt, int* __restrict__ cursor,
    int* __restrict__ entries) {
  int t = blockIdx.x * 256 + threadIdx.x;
  int lane = threadIdx.x & 63;
  int v  = (t < NN) ? cnt[t] : 0;
  int vp = (v + 3) & ~3;          // padded length (multiple of 4)
  int sc = vp;                    // inclusive prefix of padded lengths
#pragma unroll
  for (int off = 1; off < 64; off <<= 1) {
    int u = __shfl_up(sc, off, 64);
    if (lane >= off) sc += u;
  }
  int wtotal = __shfl(sc, 63, 64);
  int base = 0;
  if (lane == 63) base = atomicAdd(gtotal, wtotal);
  base = __shfl(base, 63, 64);
  if (t < NN) {
    int s = base + sc - vp;
    rs_cnt[t] = make_int2(s, v);
    cursor[t] = 0;
    for (int k = v; k < vp; ++k) entries[s + k] = 0;  // pad -> g=0, weight 0
  }
}

__global__ __launch_bounds__(256) void k_fill(
    const int* __restrict__ groups, const int2* __restrict__ rs_cnt,
    int* __restrict__ cursor, int* __restrict__ entries) {
  int e = blockIdx.x * 256 + threadIdx.x;
  if (e >= NE) return;
  int n = groups[e];
  int pos = atomicAdd(&cursor[n], 1);
  entries[rs_cnt[n].x + pos] = e >> 6;  // store g
}

// ------- k_gather: thread per (b,n); int4 entry chunks + 8 staged Qt loads -------
__global__ __launch_bounds__(256) void k_gather(
    const float4* __restrict__ tpl4, const int2* __restrict__ rs_cnt,
    const int* __restrict__ entries, const float* __restrict__ Qt,
    float* __restrict__ out) {
  int n = blockIdx.x * 256 + threadIdx.x;
  if (n >= NN) return;
  int b = blockIdx.y;
  int2 rc = rs_cnt[n];
  int s = rc.x, c = rc.y;
  float4 y = tpl4[n];
  float p0 = 0.f, p1 = 0.f, p2 = 0.f;
  const float* Qb = Qt + (size_t)b * GN * 8;

  for (int j = 0; j < c; j += 4) {
    int4 ev = *(const int4*)(entries + s + j);  // 4-aligned, padded with g=0
    // stage all 8 loads (independent; 1-deep chain after the int4)
    const float* qp0 = Qb + (size_t)ev.x * 8;
    const float* qp1 = Qb + (size_t)ev.y * 8;
    const float* qp2 = Qb + (size_t)ev.z * 8;
    const float* qp3 = Qb + (size_t)ev.w * 8;
    float4 qa = *(const float4*)(qp0);
    float4 ta = *(const float4*)(qp0 + 4);
    float4 qb = *(const float4*)(qp1);
    float4 tb = *(const float4*)(qp1 + 4);
    float4 qc = *(const float4*)(qp2);
    float4 tc = *(const float4*)(qp2 + 4);
    float4 qd = *(const float4*)(qp3);
    float4 td = *(const float4*)(qp3 + 4);
#define QACC(Q, T, K)                                                   \
    {                                                                   \
      float w = (j + (K) < c) ? 1.f : 0.f;                              \
      float tx = 2.f * ((Q).y * y.z - (Q).z * y.y);                     \
      float ty = 2.f * ((Q).z * y.x - (Q).x * y.z);                     \
      float tz = 2.f * ((Q).x * y.y - (Q).y * y.x);                     \
      p0 += w * (y.x + (Q).w * tx + ((Q).y * tz - (Q).z * ty) + (T).x); \
      p1 += w * (y.y + (Q).w * ty + ((Q).z * tx - (Q).x * tz) + (T).y); \
      p2 += w * (y.z + (Q).w * tz + ((Q).x * ty - (Q).y * tx) + (T).z); \
    }
    QACC(qa, ta, 0)
    QACC(qb, tb, 1)
    QACC(qc, tc, 2)
    QACC(qd, td, 3)
#undef QACC
  }
  float inv = 1.0f / fmaxf((float)c, 1.0f);
  float* o = out + ((size_t)b * NN + (size_t)n) * 3;
  *(float3*)o = make_float3(p0 * inv, p1 * inv, p2 * inv);
}

extern "C" void kernel_launch(void* const* d_in, const int* in_sizes, int n_in,
                              void* d_out, int out_size, void* d_ws, size_t ws_size,
                              hipStream_t stream) {
  const float* x      = (const float*)d_in[0];  // (B,N,3) f32
  const float* tpl    = (const float*)d_in[1];  // (N,3) f32
  const int*   groups = (const int*)d_in[2];    // (GN,GS) i32
  float* out = (float*)d_out;

  char* ws = (char*)d_ws;
  // Non-aliased layout, ~39.3 MB:
  size_t o_x4   = 0;                        // 25,600,000
  size_t o_tpl4 = o_x4 + 25600000;          //  1,600,000
  size_t o_yg   = o_tpl4 + 1600000;         //  3,145,728
  size_t o_ht   = o_yg + 3145728;           //  3,145,728
  size_t o_qt   = o_ht + 3145728;           //  2,097,152 (32 B rows)
  size_t o_gmy  = o_qt + 2097152;           //     65,536
  size_t o_cnt  = o_gmy + 65536;            //    400,000
  size_t o_rsc  = o_cnt + 400000;           //    800,000
  size_t o_cur  = o_rsc + 800000;           //    400,000
  size_t o_gt   = o_cur + 400000;           //         64
  size_t o_ent  = o_gt + 64;                //  2,097,152 (padded rows)
  float* x4     = (float*)(ws + o_x4);
  float* tpl4   = (float*)(ws + o_tpl4);
  float* Yg     = (float*)(ws + o_yg);
  float* Ht     = (float*)(ws + o_ht);
  float* Qt     = (float*)(ws + o_qt);
  float* GmY    = (float*)(ws + o_gmy);
  int*   cnt    = (int*)(ws + o_cnt);
  int2*  rs_cnt = (int2*)(ws + o_rsc);
  int*   cursor = (int*)(ws + o_cur);
  int*   gtotal = (int*)(ws + o_gt);
  int*   entries= (int*)(ws + o_ent);

  k_xpad<<<(BB * NN / 4 + 255) / 256, 256, 0, stream>>>(
      (const float4*)x, (const float4*)tpl, (float4*)x4, (float4*)tpl4,
      (int4*)cnt, gtotal);
  k_tpl<<<GN / 4, 256, 0, stream>>>((const float4*)tpl4, groups, Yg, GmY, cnt);
  k_stats<<<NP / 16, 256, 0, stream>>>((const float4*)x4, Yg, GmY, groups, Ht);
  k_alloc<<<NBLK, 256, 0, stream>>>(cnt, gtotal, rs_cnt, cursor, entries);
  k_fill<<<NE / 256, 256, 0, stream>>>(groups, rs_cnt, cursor, entries);
  k_svd<<<NP / 256, 256, 0, stream>>>(Ht, GmY, Qt);
  k_gather<<<dim3(NBLK, BB), 256, 0, stream>>>(
      (const float4*)tpl4, rs_cnt, entries, Qt, out);
}

// Round 11
// 122.500 us; speedup vs baseline: 1.4649x; 1.1552x over previous
//
#include <hip/hip_runtime.h>
#include <math.h>

static constexpr int BB = 16;
static constexpr int NN = 100000;
static constexpr int GN = 4096;
static constexpr int GS = 64;
static constexpr int NP = BB * GN;       // 65536 problems
static constexpr int NE = GN * GS;       // 262144 entries
static constexpr int NBLK = (NN + 255) / 256;  // 391

__device__ __forceinline__ float wsum64(float v) {
#pragma unroll
  for (int off = 32; off > 0; off >>= 1) v += __shfl_xor(v, off, 64);
  return v;
}

// ---------- k_zero: zero cnt + gtotal ----------
__global__ __launch_bounds__(256) void k_zero(
    int4* __restrict__ cnt4, int* __restrict__ gtotal) {
  int t = blockIdx.x * 256 + threadIdx.x;
  if (t == 0) *gtotal = 0;
  if (t < NN / 4) cnt4[t] = make_int4(0, 0, 0, 0);
}

// ---------- k_tpl: template pack + muY + histogram + per-entry rank ----------
__global__ __launch_bounds__(256) void k_tpl(
    const float* __restrict__ tpl, const int* __restrict__ groups,
    float* __restrict__ Yg, float* __restrict__ GmY,
    int* __restrict__ cnt, int* __restrict__ epos) {
  int g    = blockIdx.x * 4 + (threadIdx.x >> 6);
  int lane = threadIdx.x & 63;
  int e    = g * GS + lane;
  int idx = groups[e];
  int pos = atomicAdd(&cnt[idx], 1);
  epos[e] = pos;                        // rank within row n=idx (coalesced)
  float3 y = *(const float3*)(tpl + (size_t)idx * 3);
  float* o = Yg + ((size_t)g * GS + lane) * 3;
  o[0] = y.x; o[1] = y.y; o[2] = y.z;
  float sy0 = wsum64(y.x), sy1 = wsum64(y.y), sy2 = wsum64(y.z);
  if (lane == 0) {
    const float inv = 1.0f / 64.0f;
    *(float4*)(GmY + (size_t)g * 4) =
        make_float4(sy0 * inv, sy1 * inv, sy2 * inv, 0.0f);
  }
}

// ---------- k_stats: 16-lane subgroups, 4 problems/wave, 4 points/lane ----------
__global__ __launch_bounds__(256) void k_stats(
    const float* __restrict__ x, const float* __restrict__ Yg,
    const float* __restrict__ GmY, const int* __restrict__ groups,
    float* __restrict__ Ht) {
  int bid  = (blockIdx.x & 7) * 512 + (blockIdx.x >> 3);  // XCD swizzle
  int wid4 = bid * 4 + (threadIdx.x >> 6);
  int lane = threadIdx.x & 63;
  int s    = lane >> 4;
  int l4   = lane & 15;
  int p = wid4 * 4 + s;
  int b = p >> 12;
  int g = p & (GN - 1);

  int4 iv = *(const int4*)(groups + (size_t)g * GS + l4 * 4);
  const float4* yv = (const float4*)(Yg + ((size_t)g * GS + l4 * 4) * 3);
  float4 ya = yv[0], yb = yv[1], yc = yv[2];

  const float* xb = x + (size_t)b * NN * 3;
  float sx0 = 0.f, sx1 = 0.f, sx2 = 0.f;
  float h00 = 0.f, h01 = 0.f, h02 = 0.f;
  float h10 = 0.f, h11 = 0.f, h12 = 0.f;
  float h20 = 0.f, h21 = 0.f, h22 = 0.f;

#define ACC(Y0, Y1, Y2, IDX)                                   \
  {                                                            \
    float3 xv = *(const float3*)(xb + (size_t)(IDX) * 3);      \
    sx0 += xv.x; sx1 += xv.y; sx2 += xv.z;                     \
    h00 += (Y0) * xv.x; h01 += (Y0) * xv.y; h02 += (Y0) * xv.z;\
    h10 += (Y1) * xv.x; h11 += (Y1) * xv.y; h12 += (Y1) * xv.z;\
    h20 += (Y2) * xv.x; h21 += (Y2) * xv.y; h22 += (Y2) * xv.z;\
  }
  ACC(ya.x, ya.y, ya.z, iv.x);
  ACC(ya.w, yb.x, yb.y, iv.y);
  ACC(yb.z, yb.w, yc.x, iv.z);
  ACC(yc.y, yc.z, yc.w, iv.w);
#undef ACC

#define RED(V)                                                 \
  V += __shfl_xor(V, 8, 64); V += __shfl_xor(V, 4, 64);        \
  V += __shfl_xor(V, 2, 64); V += __shfl_xor(V, 1, 64);
  RED(sx0) RED(sx1) RED(sx2)
  RED(h00) RED(h01) RED(h02)
  RED(h10) RED(h11) RED(h12)
  RED(h20) RED(h21) RED(h22)
#undef RED

  if (l4 == 0) {
    const float inv = 1.0f / 64.0f;
    float4 m = *(const float4*)(GmY + (size_t)g * 4);
    float mx0 = sx0 * inv, mx1 = sx1 * inv, mx2 = sx2 * inv;
    float4 o0 = make_float4(mx0, mx1, mx2, h00 - m.x * sx0);
    float4 o1 = make_float4(h01 - m.x * sx1, h02 - m.x * sx2,
                            h10 - m.y * sx0, h11 - m.y * sx1);
    float4 o2 = make_float4(h12 - m.y * sx2, h20 - m.z * sx0,
                            h21 - m.z * sx1, h22 - m.z * sx2);
    float* o = Ht + (size_t)p * 12;
    *(float4*)(o + 0) = o0;
    *(float4*)(o + 4) = o1;
    *(float4*)(o + 8) = o2;
  }
}

// ------- k_svd: per-thread 3x3 SVD -> quaternion + t (32 B row) -------
#define JROT(P, Q, RR)                                                        \
  {                                                                           \
    float apq = K[P][Q];                                                      \
    if (fabsf(apq) > 1e-30f) {                                                \
      float app = K[P][P], aqq = K[Q][Q];                                     \
      float tau = (aqq - app) / (2.0f * apq);                                 \
      float tt = copysignf(1.0f, tau) / (fabsf(tau) + sqrtf(1.0f + tau*tau)); \
      float cc = 1.0f / sqrtf(1.0f + tt * tt);                                \
      float ss = tt * cc;                                                     \
      K[P][P] = app - tt * apq;                                               \
      K[Q][Q] = aqq + tt * apq;                                               \
      K[P][Q] = 0.0f; K[Q][P] = 0.0f;                                         \
      float krp = K[RR][P], krq = K[RR][Q];                                   \
      K[RR][P] = cc * krp - ss * krq; K[P][RR] = K[RR][P];                    \
      K[RR][Q] = ss * krp + cc * krq; K[Q][RR] = K[RR][Q];                    \
      float v0p = V[0][P], v0q = V[0][Q];                                     \
      float v1p = V[1][P], v1q = V[1][Q];                                     \
      float v2p = V[2][P], v2q = V[2][Q];                                     \
      V[0][P] = cc * v0p - ss * v0q; V[0][Q] = ss * v0p + cc * v0q;           \
      V[1][P] = cc * v1p - ss * v1q; V[1][Q] = ss * v1p + cc * v1q;           \
      V[2][P] = cc * v2p - ss * v2q; V[2][Q] = ss * v2p + cc * v2q;           \
    }                                                                         \
  }

#define FIN(AA, BBi, CC)                                                      \
  {                                                                           \
    float va0 = V[0][AA], va1 = V[1][AA], va2 = V[2][AA];                     \
    float vb0 = V[0][BBi], vb1 = V[1][BBi], vb2 = V[2][BBi];                  \
    float vc0 = V[0][CC], vc1 = V[1][CC], vc2 = V[2][CC];                     \
    float ua0 = A[0][0]*va0 + A[0][1]*va1 + A[0][2]*va2;                      \
    float ua1 = A[1][0]*va0 + A[1][1]*va1 + A[1][2]*va2;                      \
    float ua2 = A[2][0]*va0 + A[2][1]*va1 + A[2][2]*va2;                      \
    float il = 1.0f / sqrtf(ua0*ua0 + ua1*ua1 + ua2*ua2 + 1e-30f);            \
    ua0 *= il; ua1 *= il; ua2 *= il;                                          \
    float ub0 = A[0][0]*vb0 + A[0][1]*vb1 + A[0][2]*vb2;                      \
    float ub1 = A[1][0]*vb0 + A[1][1]*vb1 + A[1][2]*vb2;                      \
    float ub2 = A[2][0]*vb0 + A[2][1]*vb1 + A[2][2]*vb2;                      \
    il = 1.0f / sqrtf(ub0*ub0 + ub1*ub1 + ub2*ub2 + 1e-30f);                  \
    ub0 *= il; ub1 *= il; ub2 *= il;                                          \
    float dd = ua0*ub0 + ua1*ub1 + ua2*ub2;                                   \
    ub0 -= dd * ua0; ub1 -= dd * ua1; ub2 -= dd * ua2;                        \
    il = 1.0f / sqrtf(ub0*ub0 + ub1*ub1 + ub2*ub2 + 1e-30f);                  \
    ub0 *= il; ub1 *= il; ub2 *= il;                                          \
    float uc0 = ua1*ub2 - ua2*ub1;                                            \
    float uc1 = ua2*ub0 - ua0*ub2;                                            \
    float uc2 = ua0*ub1 - ua1*ub0;                                            \
    R[0][0] = va0*ua0 + vb0*ub0 + dsg*vc0*uc0;                                \
    R[0][1] = va0*ua1 + vb0*ub1 + dsg*vc0*uc1;                                \
    R[0][2] = va0*ua2 + vb0*ub2 + dsg*vc0*uc2;                                \
    R[1][0] = va1*ua0 + vb1*ub0 + dsg*vc1*uc0;                                \
    R[1][1] = va1*ua1 + vb1*ub1 + dsg*vc1*uc1;                                \
    R[1][2] = va1*ua2 + vb1*ub2 + dsg*vc1*uc2;                                \
    R[2][0] = va2*ua0 + vb2*ub0 + dsg*vc2*uc0;                                \
    R[2][1] = va2*ua1 + vb2*ub1 + dsg*vc2*uc1;                                \
    R[2][2] = va2*ua2 + vb2*ub2 + dsg*vc2*uc2;                                \
  }

__global__ __launch_bounds__(256) void k_svd(
    const float* __restrict__ Ht, const float* __restrict__ GmY,
    float* __restrict__ Qt) {
  int p = blockIdx.x * 256 + threadIdx.x;
  if (p >= NP) return;
  int g = p & (GN - 1);
  const float* h = Ht + (size_t)p * 12;
  float4 f0 = *(const float4*)(h + 0);
  float4 f1 = *(const float4*)(h + 4);
  float4 f2 = *(const float4*)(h + 8);
  float4 m  = *(const float4*)(GmY + (size_t)g * 4);
  float mx0 = f0.x, mx1 = f0.y, mx2 = f0.z;
  float my0 = m.x, my1 = m.y, my2 = m.z;
  float A[3][3];
  A[0][0] = f0.w; A[0][1] = f1.x; A[0][2] = f1.y;
  A[1][0] = f1.z; A[1][1] = f1.w; A[1][2] = f2.x;
  A[2][0] = f2.y; A[2][1] = f2.z; A[2][2] = f2.w;

  float K[3][3];
#pragma unroll
  for (int i = 0; i < 3; ++i)
#pragma unroll
    for (int j = 0; j < 3; ++j)
      K[i][j] = A[0][i]*A[0][j] + A[1][i]*A[1][j] + A[2][i]*A[2][j];

  float V[3][3] = {{1.f,0.f,0.f},{0.f,1.f,0.f},{0.f,0.f,1.f}};
#pragma unroll
  for (int sweep = 0; sweep < 5; ++sweep) {
    JROT(0, 1, 2);
    JROT(0, 2, 1);
    JROT(1, 2, 0);
  }

  float d0 = K[0][0], d1 = K[1][1], d2 = K[2][2];
  float detV = V[0][0]*(V[1][1]*V[2][2] - V[1][2]*V[2][1])
             - V[0][1]*(V[1][0]*V[2][2] - V[1][2]*V[2][0])
             + V[0][2]*(V[1][0]*V[2][1] - V[1][1]*V[2][0]);
  float dsg = (detV < 0.0f) ? -1.0f : 1.0f;

  float R[3][3];
  if (d0 <= d1 && d0 <= d2) {
    FIN(1, 2, 0);
  } else if (d1 <= d0 && d1 <= d2) {
    FIN(2, 0, 1);
  } else {
    FIN(0, 1, 2);
  }

  float t0 = mx0 - (R[0][0]*my0 + R[0][1]*my1 + R[0][2]*my2);
  float t1 = mx1 - (R[1][0]*my0 + R[1][1]*my1 + R[1][2]*my2);
  float t2 = mx2 - (R[2][0]*my0 + R[2][1]*my1 + R[2][2]*my2);

  // R (proper rotation, det=+1) -> quaternion (x,y,z,w)
  float qw, qx, qy, qz;
  float tr = R[0][0] + R[1][1] + R[2][2];
  if (tr > 0.f) {
    float S = sqrtf(tr + 1.0f) * 2.0f;
    qw = 0.25f * S;
    qx = (R[2][1] - R[1][2]) / S;
    qy = (R[0][2] - R[2][0]) / S;
    qz = (R[1][0] - R[0][1]) / S;
  } else if (R[0][0] > R[1][1] && R[0][0] > R[2][2]) {
    float S = sqrtf(1.0f + R[0][0] - R[1][1] - R[2][2]) * 2.0f;
    qw = (R[2][1] - R[1][2]) / S;
    qx = 0.25f * S;
    qy = (R[0][1] + R[1][0]) / S;
    qz = (R[0][2] + R[2][0]) / S;
  } else if (R[1][1] > R[2][2]) {
    float S = sqrtf(1.0f + R[1][1] - R[0][0] - R[2][2]) * 2.0f;
    qw = (R[0][2] - R[2][0]) / S;
    qx = (R[0][1] + R[1][0]) / S;
    qy = 0.25f * S;
    qz = (R[1][2] + R[2][1]) / S;
  } else {
    float S = sqrtf(1.0f + R[2][2] - R[0][0] - R[1][1]) * 2.0f;
    qw = (R[1][0] - R[0][1]) / S;
    qx = (R[0][2] + R[2][0]) / S;
    qy = (R[1][2] + R[2][1]) / S;
    qz = 0.25f * S;
  }
  float il2 = 1.0f / sqrtf(qw*qw + qx*qx + qy*qy + qz*qz);
  qw *= il2; qx *= il2; qy *= il2; qz *= il2;

  float* o = Qt + (size_t)p * 8;  // 32 B row
  *(float4*)(o + 0) = make_float4(qx, qy, qz, qw);
  *(float4*)(o + 4) = make_float4(t0, t1, t2, 0.f);
}

// ---- k_alloc: 4-aligned CSR row allocation + zero-pad entries tail ----
__global__ __launch_bounds__(256) void k_alloc(
    const int* __restrict__ cnt, int* __restrict__ gtotal,
    int2* __restrict__ rs_cnt, int* __restrict__ entries) {
  int t = blockIdx.x * 256 + threadIdx.x;
  int lane = threadIdx.x & 63;
  int v  = (t < NN) ? cnt[t] : 0;
  int vp = (v + 3) & ~3;          // padded length (multiple of 4)
  int sc = vp;
#pragma unroll
  for (int off = 1; off < 64; off <<= 1) {
    int u = __shfl_up(sc, off, 64);
    if (lane >= off) sc += u;
  }
  int wtotal = __shfl(sc, 63, 64);
  int base = 0;
  if (lane == 63) base = atomicAdd(gtotal, wtotal);
  base = __shfl(base, 63, 64);
  if (t < NN) {
    int s = base + sc - vp;
    rs_cnt[t] = make_int2(s, v);
    for (int k = v; k < vp; ++k) entries[s + k] = 0;  // pad -> g=0, weight 0
  }
}

// ---- k_fill: atomic-free (rank precomputed in k_tpl) ----
__global__ __launch_bounds__(256) void k_fill(
    const int* __restrict__ groups, const int2* __restrict__ rs_cnt,
    const int* __restrict__ epos, int* __restrict__ entries) {
  int e = blockIdx.x * 256 + threadIdx.x;
  if (e >= NE) return;
  int n = groups[e];
  entries[rs_cnt[n].x + epos[e]] = e >> 6;  // store g
}

// ------- k_gather: fused grid, 2 b-planes pinned per XCD -------
__global__ __launch_bounds__(256) void k_gather(
    const float* __restrict__ tpl, const int2* __restrict__ rs_cnt,
    const int* __restrict__ entries, const float* __restrict__ Qt,
    float* __restrict__ out) {
  // 6256 blocks = 8 XCDs x 2 b-planes x 391 n-blocks.
  // Consecutive blockIdx round-robin across XCDs -> xcd = bid & 7 owns
  // b in {2*xcd, 2*xcd+1}: Qt working set 256 KB per XCD L2.
  int bid = blockIdx.x;
  int xcd = bid & 7;
  int i   = bid >> 3;              // 0..781
  int b   = xcd * 2 + (i / NBLK);
  int nb  = i % NBLK;
  int n   = nb * 256 + threadIdx.x;
  if (n >= NN) return;
  int2 rc = rs_cnt[n];
  int s = rc.x, c = rc.y;
  float3 y = *(const float3*)(tpl + (size_t)n * 3);
  float p0 = 0.f, p1 = 0.f, p2 = 0.f;
  const float* Qb = Qt + (size_t)b * GN * 8;

  for (int j = 0; j < c; j += 4) {
    int4 ev = *(const int4*)(entries + s + j);  // 4-aligned, padded with g=0
    const float* qp0 = Qb + (size_t)ev.x * 8;
    const float* qp1 = Qb + (size_t)ev.y * 8;
    const float* qp2 = Qb + (size_t)ev.z * 8;
    const float* qp3 = Qb + (size_t)ev.w * 8;
    float4 qa = *(const float4*)(qp0);
    float4 ta = *(const float4*)(qp0 + 4);
    float4 qb = *(const float4*)(qp1);
    float4 tb = *(const float4*)(qp1 + 4);
    float4 qc = *(const float4*)(qp2);
    float4 tc = *(const float4*)(qp2 + 4);
    float4 qd = *(const float4*)(qp3);
    float4 td = *(const float4*)(qp3 + 4);
#define QACC(Q, T, K)                                                   \
    {                                                                   \
      float w = (j + (K) < c) ? 1.f : 0.f;                              \
      float tx = 2.f * ((Q).y * y.z - (Q).z * y.y);                     \
      float ty = 2.f * ((Q).z * y.x - (Q).x * y.z);                     \
      float tz = 2.f * ((Q).x * y.y - (Q).y * y.x);                     \
      p0 += w * (y.x + (Q).w * tx + ((Q).y * tz - (Q).z * ty) + (T).x); \
      p1 += w * (y.y + (Q).w * ty + ((Q).z * tx - (Q).x * tz) + (T).y); \
      p2 += w * (y.z + (Q).w * tz + ((Q).x * ty - (Q).y * tx) + (T).z); \
    }
    QACC(qa, ta, 0)
    QACC(qb, tb, 1)
    QACC(qc, tc, 2)
    QACC(qd, td, 3)
#undef QACC
  }
  float inv = 1.0f / fmaxf((float)c, 1.0f);
  float* o = out + ((size_t)b * NN + (size_t)n) * 3;
  *(float3*)o = make_float3(p0 * inv, p1 * inv, p2 * inv);
}

extern "C" void kernel_launch(void* const* d_in, const int* in_sizes, int n_in,
                              void* d_out, int out_size, void* d_ws, size_t ws_size,
                              hipStream_t stream) {
  const float* x      = (const float*)d_in[0];  // (B,N,3) f32
  const float* tpl    = (const float*)d_in[1];  // (N,3) f32
  const int*   groups = (const int*)d_in[2];    // (GN,GS) i32
  float* out = (float*)d_out;

  char* ws = (char*)d_ws;
  // Non-aliased layout, ~12.8 MB:
  size_t o_yg   = 0;                        //  3,145,728
  size_t o_ht   = o_yg + 3145728;           //  3,145,728
  size_t o_qt   = o_ht + 3145728;           //  2,097,152 (32 B rows)
  size_t o_gmy  = o_qt + 2097152;           //     65,536
  size_t o_cnt  = o_gmy + 65536;            //    400,000
  size_t o_rsc  = o_cnt + 400000;           //    800,000
  size_t o_gt   = o_rsc + 800000;           //         64
  size_t o_epos = o_gt + 64;                //  1,048,576
  size_t o_ent  = o_epos + 1048576;         //  2,097,152 (padded rows)
  float* Yg     = (float*)(ws + o_yg);
  float* Ht     = (float*)(ws + o_ht);
  float* Qt     = (float*)(ws + o_qt);
  float* GmY    = (float*)(ws + o_gmy);
  int*   cnt    = (int*)(ws + o_cnt);
  int2*  rs_cnt = (int2*)(ws + o_rsc);
  int*   gtotal = (int*)(ws + o_gt);
  int*   epos   = (int*)(ws + o_epos);
  int*   entries= (int*)(ws + o_ent);

  k_zero<<<(NN / 4 + 255) / 256, 256, 0, stream>>>((int4*)cnt, gtotal);
  k_tpl<<<GN / 4, 256, 0, stream>>>(tpl, groups, Yg, GmY, cnt, epos);
  k_stats<<<NP / 16, 256, 0, stream>>>(x, Yg, GmY, groups, Ht);
  k_svd<<<NP / 256, 256, 0, stream>>>(Ht, GmY, Qt);
  k_alloc<<<NBLK, 256, 0, stream>>>(cnt, gtotal, rs_cnt, entries);
  k_fill<<<NE / 256, 256, 0, stream>>>(groups, rs_cnt, epos, entries);
  k_gather<<<8 * 2 * NBLK, 256, 0, stream>>>(tpl, rs_cnt, entries, Qt, out);
}